// Round 8
// baseline (143.517 us; speedup 1.0000x reference)
//
#include <hip/hip_runtime.h>
#include <hip/hip_bf16.h>
#include <stdint.h>

typedef __attribute__((ext_vector_type(4))) float fv4;
typedef __attribute__((ext_vector_type(4))) short sv4;
typedef __attribute__((ext_vector_type(8))) short sv8;

#define SCHUNK 2048
#define FPB 64      // facets per block (16 per wave, 4 waves)
#define PZB 108     // Z row pitch (shorts), R4/R5/R7-validated

static __device__ __forceinline__ short f2bf(float f) {
  __hip_bfloat16 h = __float2bfloat16(f);   // HW v_cvt, RNE
  union { __hip_bfloat16 h; short s; } u; u.h = h;
  return u.s;
}

// ---------------- scan: offsets from num_texture (R1-validated) ----------------
__global__ __launch_bounds__(256) void scan1(const int* __restrict__ num, int nf,
                                             int* __restrict__ bsum) {
  __shared__ int sd[256];
  int b = blockIdx.x, tid = threadIdx.x;
  int base = b * SCHUNK + tid * 8;
  int s = 0;
#pragma unroll
  for (int j = 0; j < 8; ++j) { int i = base + j; if (i < nf) s += num[i]; }
  sd[tid] = s; __syncthreads();
  for (int st = 128; st > 0; st >>= 1) {
    if (tid < st) sd[tid] += sd[tid + st];
    __syncthreads();
  }
  if (tid == 0) bsum[b] = sd[0];
}

__global__ __launch_bounds__(256) void scan2(int* __restrict__ bsum, int nb) {
  __shared__ int sd[256];
  int tid = threadIdx.x;
  int v = (tid < nb) ? bsum[tid] : 0;
  sd[tid] = v; __syncthreads();
  for (int off = 1; off < 256; off <<= 1) {
    int t = (tid >= off) ? sd[tid - off] : 0;
    __syncthreads();
    sd[tid] += t;
    __syncthreads();
  }
  if (tid < nb) bsum[tid] = sd[tid] - v;   // exclusive prefix
}

__global__ __launch_bounds__(256) void scan3(const int* __restrict__ num, int nf,
                                             const int* __restrict__ bsum,
                                             int* __restrict__ offsets) {
  __shared__ int sc_[256];
  int b = blockIdx.x, tid = threadIdx.x;
  int base = b * SCHUNK + tid * 8;
  int loc[8]; int s = 0;
#pragma unroll
  for (int j = 0; j < 8; ++j) {
    loc[j] = (base + j < nf) ? num[base + j] : 0;
    s += loc[j];
  }
  sc_[tid] = s; __syncthreads();
  for (int off = 1; off < 256; off <<= 1) {
    int t = (tid >= off) ? sc_[tid - off] : 0;
    __syncthreads();
    sc_[tid] += t;
    __syncthreads();
  }
  int run = bsum[b] + sc_[tid] - s;
#pragma unroll
  for (int j = 0; j < 8; ++j) {
    if (base + j < nf) offsets[base + j] = run;
    run += loc[j];
  }
  if (b == gridDim.x - 1 && tid == 255) offsets[nf] = run;
}

// ---------------- prep: W -> bf16 w2g[o*96 + k*32 + c], once for whole grid ----------------
__global__ __launch_bounds__(256) void k_prep(const float* __restrict__ W,
                                              short* __restrict__ w2g) {
  for (int i = threadIdx.x; i < 3072; i += 256) {
    int o = i / 96;
    int ck = i - o * 96;
    int k = ck >> 5, c = ck & 31;
    w2g[o * 96 + ck] = f2bf(W[o * 96 + c * 3 + k]);
  }
}

// ---------------- main: barrier-free, one wave = 16 facets ----------------
// fold (regs) -> Z (wave-private LDS) -> MFMA (B from global w2g) -> reg epilogue
__global__ __launch_bounds__(256) void k_main(
    const float* __restrict__ x, const float* __restrict__ bary,
    const short* __restrict__ w2g, const float* __restrict__ bias,
    const int* __restrict__ offsets, float* __restrict__ out,
    float* __restrict__ partials, int nf, int nw)
{
  __shared__ short Z[4 * 16 * PZB];    // 13824 B; 4 disjoint wave-private quarters

  const int tid = threadIdx.x;
  const int lane = tid & 63;
  const int wv = tid >> 6;
  const int f0 = blockIdx.x * FPB + wv * 16;   // this wave's facet base
  short* Zw = &Z[wv * 16 * PZB];

  // ---- fold: one thread per (facet, 8-ch quarter)  (R7-validated math) ----
  const int fl = lane >> 2;            // 0..15
  const int cb = (lane & 3) * 8;       // 0,8,16,24
  const int f = f0 + fl;
  const int fa = f < nf ? f : nf;
  const int fb = (f + 1) < nf ? (f + 1) : nf;
  const int st = offsets[fa];
  const int en = offsets[fb];
  const int nm_my = en - st;

  {
    float z0[8], z1[8], z2[8];
#pragma unroll
    for (int j = 0; j < 8; ++j) { z0[j] = 0.f; z1[j] = 0.f; z2[j] = 0.f; }

    if (nm_my == 3) {
      // fast path: all loads issued up-front, fully independent
      fv4 xs[3][2];
      float bb[3][3];
#pragma unroll
      for (int s = 0; s < 3; ++s) {
        const float* xp = x + (size_t)(st + s) * 32 + cb;
        xs[s][0] = *(const fv4*)(xp);
        xs[s][1] = *(const fv4*)(xp + 4);
      }
#pragma unroll
      for (int s = 0; s < 3; ++s) {
        const float* bp = bary + (size_t)(st + s) * 3;
        bb[s][0] = bp[0]; bb[s][1] = bp[1]; bb[s][2] = bp[2];
      }
#pragma unroll
      for (int s = 0; s < 3; ++s)
#pragma unroll
        for (int q = 0; q < 2; ++q)
#pragma unroll
          for (int j = 0; j < 4; ++j) {
            float xv = xs[s][q][j];
            z0[q * 4 + j] += xv * bb[s][0];
            z1[q * 4 + j] += xv * bb[s][1];
            z2[q * 4 + j] += xv * bb[s][2];
          }
    } else {
      // generic ragged path
      for (int t = st; t < en; ++t) {
        const float* xp = x + (size_t)t * 32 + cb;
        fv4 xa = *(const fv4*)(xp);
        fv4 xb = *(const fv4*)(xp + 4);
        const float* bp = bary + (size_t)t * 3;
        float b0 = bp[0], b1 = bp[1], b2 = bp[2];
#pragma unroll
        for (int j = 0; j < 4; ++j) {
          z0[j]     += xa[j] * b0; z1[j]     += xa[j] * b1; z2[j]     += xa[j] * b2;
          z0[4 + j] += xb[j] * b0; z1[4 + j] += xb[j] * b1; z2[4 + j] += xb[j] * b2;
        }
      }
    }

    // write Z row segment: [fl][k*32 + cb .. +8) for k=0,1,2  (wave-private)
    short* zr = &Zw[fl * PZB + cb];
#pragma unroll
    for (int g = 0; g < 2; ++g) {
      sv4 p0, p1, p2;
#pragma unroll
      for (int j = 0; j < 4; ++j) {
        p0[j] = f2bf(z0[g * 4 + j]);
        p1[j] = f2bf(z1[g * 4 + j]);
        p2[j] = f2bf(z2[g * 4 + j]);
      }
      *(sv4*)(zr + g * 4)      = p0;
      *(sv4*)(zr + 32 + g * 4) = p1;
      *(sv4*)(zr + 64 + g * 4) = p2;
    }
  }

  // intra-wave only: DS ops from one wave complete in order; fence the scheduler.
  __builtin_amdgcn_wave_barrier();

  // ---- MFMA: M=16 (this wave's facets), N=32, K=96  (R7-validated addressing, wv folded) ----
  const int rowl = lane & 15;
  const int grp = lane >> 4;

  fv4 acc[2];
  acc[0] = (fv4){0.f, 0.f, 0.f, 0.f};
  acc[1] = (fv4){0.f, 0.f, 0.f, 0.f};

#pragma unroll
  for (int kb = 0; kb < 3; ++kb) {
    const int cko = kb * 32 + grp * 4;
    sv8 bfr[2];
#pragma unroll
    for (int n = 0; n < 2; ++n) {
      const short* wr = w2g + (n * 16 + rowl) * 96 + cko;   // global, L1-broadcast
      sv4 lo = *(const sv4*)(wr);
      sv4 hi = *(const sv4*)(wr + 16);
#pragma unroll
      for (int j = 0; j < 4; ++j) { bfr[n][j] = lo[j]; bfr[n][4 + j] = hi[j]; }
    }
    const short* zr = &Zw[rowl * PZB + cko];
    sv4 lo = *(const sv4*)(zr);
    sv4 hi = *(const sv4*)(zr + 16);
    sv8 afr;
#pragma unroll
    for (int j = 0; j < 4; ++j) { afr[j] = lo[j]; afr[4 + j] = hi[j]; }
    acc[0] = __builtin_amdgcn_mfma_f32_16x16x32_bf16(afr, bfr[0], acc[0], 0, 0, 0);
    acc[1] = __builtin_amdgcn_mfma_f32_16x16x32_bf16(afr, bfr[1], acc[1], 0, 0, 0);
  }

  // ---- register epilogue: out[(f0+grp*4+r)*32 + n*16+rowl] = relu(acc[n][r]/nm + bias) ----
  // (identical to validated yt-write composed with validated finalize read)
  float bo0 = bias[rowl];
  float bo1 = bias[16 + rowl];
  float s1l = 0.f, s1h = 0.f, s2l = 0.f, s2h = 0.f;
#pragma unroll
  for (int r = 0; r < 4; ++r) {
    int row = grp * 4 + r;
    int fr = f0 + row;
    int nm = __shfl(nm_my, row * 4, 64);     // folder lane of that facet
    float den = (float)(nm > 1 ? nm : 1);
    float inv = 1.0f / den;
    if (fr < nf) {
      float v0 = fmaxf(acc[0][r] * inv + bo0, 0.f);
      float v1 = fmaxf(acc[1][r] * inv + bo1, 0.f);
      out[fr * 32 + rowl]      = v0;
      out[fr * 32 + 16 + rowl] = v1;
      s1l += v0; s2l += v0 * v0;
      s1h += v1; s2h += v1 * v1;
    }
  }
  // reduce across the 4 lanes sharing rowl (xor bits 4,5); deterministic
  s1l += __shfl_xor(s1l, 16, 64); s1l += __shfl_xor(s1l, 32, 64);
  s1h += __shfl_xor(s1h, 16, 64); s1h += __shfl_xor(s1h, 32, 64);
  s2l += __shfl_xor(s2l, 16, 64); s2l += __shfl_xor(s2l, 32, 64);
  s2h += __shfl_xor(s2h, 16, 64); s2h += __shfl_xor(s2h, 32, 64);
  if (grp == 0) {
    int w = blockIdx.x * 4 + wv;
    partials[(long)(rowl)      * nw + w] = s1l;
    partials[(long)(16 + rowl) * nw + w] = s1h;
    partials[(long)(32 + rowl) * nw + w] = s2l;
    partials[(long)(48 + rowl) * nw + w] = s2h;
  }
}

// ---------------- reduce partials -> stats[64] (sum[32], sumsq[32]) ----------------
__global__ __launch_bounds__(256) void k_reduce(const float* __restrict__ partials,
                                                int nw, float* __restrict__ stats) {
  __shared__ float sd[256];
  int c = blockIdx.x;
  const float* p = partials + (long)c * nw;
  float s = 0.f;
  for (int i = threadIdx.x; i < nw; i += 256) s += p[i];
  sd[threadIdx.x] = s; __syncthreads();
  for (int st = 128; st > 0; st >>= 1) {
    if (threadIdx.x < st) sd[threadIdx.x] += sd[threadIdx.x + st];
    __syncthreads();
  }
  if (threadIdx.x == 0) stats[c] = sd[0];
}

// ---------------- BN apply, in place on out ----------------
__global__ __launch_bounds__(256) void k_bn(float* __restrict__ out,
                                            const float* __restrict__ stats,
                                            const float* __restrict__ gamma,
                                            const float* __restrict__ beta, int nf) {
  __shared__ float sc[32], sh[32];
  if (threadIdx.x < 32) {
    int o = threadIdx.x;
    float inv_n = 1.0f / (float)nf;
    float mean = stats[o] * inv_n;
    float var = stats[32 + o] * inv_n - mean * mean;
    float rstd = rsqrtf(var + 1e-5f);
    float g = gamma[o] * rstd;
    sc[o] = g;
    sh[o] = beta[o] - mean * g;
  }
  __syncthreads();
  long total4 = (long)nf * 8;
  long idx0 = (long)blockIdx.x * 256 + threadIdx.x;
  int ob = ((int)idx0 & 7) * 4;           // constant per thread (stride % 8 == 0)
  fv4 scv = *(const fv4*)&sc[ob];
  fv4 shv = *(const fv4*)&sh[ob];
  for (long idx = idx0; idx < total4; idx += (long)gridDim.x * 256) {
    fv4 v = *((const fv4*)out + idx);
    v = v * scv + shv;
    *((fv4*)out + idx) = v;
  }
}

extern "C" void kernel_launch(void* const* d_in, const int* in_sizes, int n_in,
                              void* d_out, int out_size, void* d_ws, size_t ws_size,
                              hipStream_t stream) {
  const float* x     = (const float*)d_in[0];
  const float* bary  = (const float*)d_in[1];
  const int*   numt  = (const int*)d_in[2];
  const float* W     = (const float*)d_in[3];
  const float* bias  = (const float*)d_in[4];
  const float* gamma = (const float*)d_in[5];
  const float* beta  = (const float*)d_in[6];
  float* out = (float*)d_out;

  const int nf   = in_sizes[2];
  const int nblk = (nf + FPB - 1) / FPB;
  const int nw   = nblk * 4;              // one partials column per wave
  const int nbS  = (nf + SCHUNK - 1) / SCHUNK;

  char* w = (char*)d_ws;
  int* offsets = (int*)w;
  size_t off1 = (4UL * (size_t)(nf + 1) + 255) & ~255UL;
  int* bsum = (int*)(w + off1);
  size_t off2 = (off1 + 4UL * (size_t)nbS + 255) & ~255UL;
  short* w2g = (short*)(w + off2);
  size_t off3 = (off2 + 2UL * 3072UL + 255) & ~255UL;
  float* partials = (float*)(w + off3);
  size_t off4 = (off3 + 4UL * 64UL * (size_t)nw + 255) & ~255UL;
  float* stats = (float*)(w + off4);

  scan1<<<nbS, 256, 0, stream>>>(numt, nf, bsum);
  scan2<<<1, 256, 0, stream>>>(bsum, nbS);
  scan3<<<nbS, 256, 0, stream>>>(numt, nf, bsum, offsets);
  k_prep<<<1, 256, 0, stream>>>(W, w2g);
  k_main<<<nblk, 256, 0, stream>>>(x, bary, w2g, bias, offsets, out, partials, nf, nw);
  k_reduce<<<64, 256, 0, stream>>>(partials, nw, stats);
  k_bn<<<2048, 256, 0, stream>>>(out, stats, gamma, beta, nf);
}

// Round 10
// 97.810 us; speedup vs baseline: 1.4673x; 1.4673x over previous
//
#include <hip/hip_runtime.h>
#include <hip/hip_bf16.h>
#include <stdint.h>

typedef __attribute__((ext_vector_type(4))) float fv4;
typedef __attribute__((ext_vector_type(4))) short sv4;
typedef __attribute__((ext_vector_type(8))) short sv8;

#define SCHUNK 2048
#define NIT 4             // tiles per wave
#define SPAN (64 * NIT)   // facets per block
#define PZB 108           // Z row pitch (shorts), validated

static __device__ __forceinline__ short f2bf(float f) {
  __hip_bfloat16 h = __float2bfloat16(f);   // HW v_cvt, RNE
  union { __hip_bfloat16 h; short s; } u; u.h = h;
  return u.s;
}

// ---------------- scan: offsets from num_texture (R1-validated) ----------------
__global__ __launch_bounds__(256) void scan1(const int* __restrict__ num, int nf,
                                             int* __restrict__ bsum) {
  __shared__ int sd[256];
  int b = blockIdx.x, tid = threadIdx.x;
  int base = b * SCHUNK + tid * 8;
  int s = 0;
#pragma unroll
  for (int j = 0; j < 8; ++j) { int i = base + j; if (i < nf) s += num[i]; }
  sd[tid] = s; __syncthreads();
  for (int st = 128; st > 0; st >>= 1) {
    if (tid < st) sd[tid] += sd[tid + st];
    __syncthreads();
  }
  if (tid == 0) bsum[b] = sd[0];
}

__global__ __launch_bounds__(256) void scan2(int* __restrict__ bsum, int nb) {
  __shared__ int sd[256];
  int tid = threadIdx.x;
  int v = (tid < nb) ? bsum[tid] : 0;
  sd[tid] = v; __syncthreads();
  for (int off = 1; off < 256; off <<= 1) {
    int t = (tid >= off) ? sd[tid - off] : 0;
    __syncthreads();
    sd[tid] += t;
    __syncthreads();
  }
  if (tid < nb) bsum[tid] = sd[tid] - v;   // exclusive prefix
}

__global__ __launch_bounds__(256) void scan3(const int* __restrict__ num, int nf,
                                             const int* __restrict__ bsum,
                                             int* __restrict__ offsets) {
  __shared__ int sc_[256];
  int b = blockIdx.x, tid = threadIdx.x;
  int base = b * SCHUNK + tid * 8;
  int loc[8]; int s = 0;
#pragma unroll
  for (int j = 0; j < 8; ++j) {
    loc[j] = (base + j < nf) ? num[base + j] : 0;
    s += loc[j];
  }
  sc_[tid] = s; __syncthreads();
  for (int off = 1; off < 256; off <<= 1) {
    int t = (tid >= off) ? sc_[tid - off] : 0;
    __syncthreads();
    sc_[tid] += t;
    __syncthreads();
  }
  int run = bsum[b] + sc_[tid] - s;
#pragma unroll
  for (int j = 0; j < 8; ++j) {
    if (base + j < nf) offsets[base + j] = run;
    run += loc[j];
  }
  if (b == gridDim.x - 1 && tid == 255) offsets[nf] = run;
}

// ---------------- main: wave-autonomous multi-tile; batched speculative loads ----------------
__global__ __launch_bounds__(256) void k_main(
    const float* __restrict__ x, const float* __restrict__ bary,
    const float* __restrict__ W, const float* __restrict__ bias,
    const int* __restrict__ offsets, float* __restrict__ out,
    float* __restrict__ partials, int nf, int nt, int nw)
{
  __shared__ short W2[32 * PZB];       // 6912 B, read-only after prologue
  __shared__ short Z[4 * 16 * PZB];    // 13824 B; 4 disjoint wave-private quarters

  const int tid = threadIdx.x;
  const int lane = tid & 63;
  const int wv = tid >> 6;
  short* Zw = &Z[wv * 16 * PZB];

  // ---- prologue: stage W2[o*PZB + k*32 + c] = bf16(W[o*96 + c*3 + k]) (validated) ----
  for (int idx = tid; idx < 3072; idx += 256) {
    int o = idx / 96;
    int ck = idx - o * 96;
    int k = ck >> 5, c = ck & 31;
    W2[o * PZB + ck] = f2bf(W[o * 96 + c * 3 + k]);
  }
  __syncthreads();   // the ONLY block barrier

  const int fl = lane >> 2;            // 0..15  (fold row)
  const int cb = (lane & 3) * 8;       // 0,8,16,24 (fold channel base)
  const int rowl = lane & 15;          // GEMM/epilogue col
  const int grp = lane >> 4;           // GEMM/epilogue row group
  const int blk0 = blockIdx.x * SPAN;

  float bo0 = bias[rowl];
  float bo1 = bias[16 + rowl];
  float s1l = 0.f, s1h = 0.f, s2l = 0.f, s2h = 0.f;

  for (int t = 0; t < NIT; ++t) {
    const int f0t = blk0 + t * 64 + wv * 16;
    const int f = f0t + fl;
    const int fa = f < nf ? f : nf;
    const int fb = (f + 1) < nf ? (f + 1) : nf;

    // ---- batched loads: offsets AND speculative x/bary, all independent ----
    const int st = offsets[fa];
    const int en = offsets[fb];
    const int s3 = 3 * f;
    const int sbase = (f < nf && s3 + 3 <= nt) ? s3 : 0;   // clamped, never OOB
    const float* xp0 = x + (size_t)(sbase + 0) * 32 + cb;
    const float* xp1 = x + (size_t)(sbase + 1) * 32 + cb;
    const float* xp2 = x + (size_t)(sbase + 2) * 32 + cb;
    fv4 x0a = *(const fv4*)(xp0), x0b = *(const fv4*)(xp0 + 4);
    fv4 x1a = *(const fv4*)(xp1), x1b = *(const fv4*)(xp1 + 4);
    fv4 x2a = *(const fv4*)(xp2), x2b = *(const fv4*)(xp2 + 4);
    const float* bp0 = bary + (size_t)(sbase + 0) * 3;
    const float* bp1 = bary + (size_t)(sbase + 1) * 3;
    const float* bp2 = bary + (size_t)(sbase + 2) * 3;
    float b00 = bp0[0], b01 = bp0[1], b02 = bp0[2];
    float b10 = bp1[0], b11 = bp1[1], b12 = bp1[2];
    float b20 = bp2[0], b21 = bp2[1], b22 = bp2[2];

    const int nm_my = en - st;

    // ---- fold (R8-validated math; speculative regs exact when st==3f) ----
    float z0[8], z1[8], z2[8];
#pragma unroll
    for (int j = 0; j < 8; ++j) { z0[j] = 0.f; z1[j] = 0.f; z2[j] = 0.f; }

    if (nm_my == 3 && st == s3) {
      // st==3f && nm==3 ⇒ en=3f+3 ≤ offsets[nf]=nt ⇒ sbase==s3: regs are the real rows
#pragma unroll
      for (int j = 0; j < 4; ++j) {
        z0[j]     += x0a[j] * b00; z1[j]     += x0a[j] * b01; z2[j]     += x0a[j] * b02;
        z0[4 + j] += x0b[j] * b00; z1[4 + j] += x0b[j] * b01; z2[4 + j] += x0b[j] * b02;
      }
#pragma unroll
      for (int j = 0; j < 4; ++j) {
        z0[j]     += x1a[j] * b10; z1[j]     += x1a[j] * b11; z2[j]     += x1a[j] * b12;
        z0[4 + j] += x1b[j] * b10; z1[4 + j] += x1b[j] * b11; z2[4 + j] += x1b[j] * b12;
      }
#pragma unroll
      for (int j = 0; j < 4; ++j) {
        z0[j]     += x2a[j] * b20; z1[j]     += x2a[j] * b21; z2[j]     += x2a[j] * b22;
        z0[4 + j] += x2b[j] * b20; z1[4 + j] += x2b[j] * b21; z2[4 + j] += x2b[j] * b22;
      }
    } else {
      // generic ragged path (R8-validated)
      for (int t2 = st; t2 < en; ++t2) {
        const float* xp = x + (size_t)t2 * 32 + cb;
        fv4 xa = *(const fv4*)(xp);
        fv4 xb = *(const fv4*)(xp + 4);
        const float* bp = bary + (size_t)t2 * 3;
        float b0 = bp[0], b1 = bp[1], b2 = bp[2];
#pragma unroll
        for (int j = 0; j < 4; ++j) {
          z0[j]     += xa[j] * b0; z1[j]     += xa[j] * b1; z2[j]     += xa[j] * b2;
          z0[4 + j] += xb[j] * b0; z1[4 + j] += xb[j] * b1; z2[4 + j] += xb[j] * b2;
        }
      }
    }

    // ---- Z write, wave-private (R8-validated) ----
    short* zr = &Zw[fl * PZB + cb];
#pragma unroll
    for (int g = 0; g < 2; ++g) {
      sv4 p0, p1, p2;
#pragma unroll
      for (int j = 0; j < 4; ++j) {
        p0[j] = f2bf(z0[g * 4 + j]);
        p1[j] = f2bf(z1[g * 4 + j]);
        p2[j] = f2bf(z2[g * 4 + j]);
      }
      *(sv4*)(zr + g * 4)      = p0;
      *(sv4*)(zr + 32 + g * 4) = p1;
      *(sv4*)(zr + 64 + g * 4) = p2;
    }
    __builtin_amdgcn_wave_barrier();   // same-wave DS in-order (R8-validated)

    // ---- GEMM M=16: A from Zw (R8-validated), B from LDS W2 (R7-validated) ----
    fv4 acc0 = (fv4){0.f, 0.f, 0.f, 0.f};
    fv4 acc1 = (fv4){0.f, 0.f, 0.f, 0.f};
#pragma unroll
    for (int kb = 0; kb < 3; ++kb) {
      const int cko = kb * 32 + grp * 4;
      sv8 bfr0, bfr1, afr;
      {
        const short* wr = &W2[rowl * PZB + cko];
        sv4 lo = *(const sv4*)(wr), hi = *(const sv4*)(wr + 16);
#pragma unroll
        for (int j = 0; j < 4; ++j) { bfr0[j] = lo[j]; bfr0[4 + j] = hi[j]; }
      }
      {
        const short* wr = &W2[(16 + rowl) * PZB + cko];
        sv4 lo = *(const sv4*)(wr), hi = *(const sv4*)(wr + 16);
#pragma unroll
        for (int j = 0; j < 4; ++j) { bfr1[j] = lo[j]; bfr1[4 + j] = hi[j]; }
      }
      {
        const short* zr2 = &Zw[rowl * PZB + cko];
        sv4 lo = *(const sv4*)(zr2), hi = *(const sv4*)(zr2 + 16);
#pragma unroll
        for (int j = 0; j < 4; ++j) { afr[j] = lo[j]; afr[4 + j] = hi[j]; }
      }
      acc0 = __builtin_amdgcn_mfma_f32_16x16x32_bf16(afr, bfr0, acc0, 0, 0, 0);
      acc1 = __builtin_amdgcn_mfma_f32_16x16x32_bf16(afr, bfr1, acc1, 0, 0, 0);
    }

    // ---- register epilogue (R8-validated) ----
#pragma unroll
    for (int r = 0; r < 4; ++r) {
      int row = grp * 4 + r;
      int fr = f0t + row;
      int nm = __shfl(nm_my, row * 4, 64);
      float inv = 1.0f / (float)(nm > 1 ? nm : 1);
      if (fr < nf) {
        float v0 = fmaxf(acc0[r] * inv + bo0, 0.f);
        float v1 = fmaxf(acc1[r] * inv + bo1, 0.f);
        out[fr * 32 + rowl]      = v0;
        out[fr * 32 + 16 + rowl] = v1;
        s1l += v0; s2l += v0 * v0;
        s1h += v1; s2h += v1 * v1;
      }
    }
    __builtin_amdgcn_wave_barrier();   // fence before next tile reuses Zw
  }

  // ---- per-wave stats -> one partials column (R8-validated reduce) ----
  s1l += __shfl_xor(s1l, 16, 64); s1l += __shfl_xor(s1l, 32, 64);
  s1h += __shfl_xor(s1h, 16, 64); s1h += __shfl_xor(s1h, 32, 64);
  s2l += __shfl_xor(s2l, 16, 64); s2l += __shfl_xor(s2l, 32, 64);
  s2h += __shfl_xor(s2h, 16, 64); s2h += __shfl_xor(s2h, 32, 64);
  if (grp == 0) {
    int w = blockIdx.x * 4 + wv;
    partials[(long)(rowl)      * nw + w] = s1l;
    partials[(long)(16 + rowl) * nw + w] = s1h;
    partials[(long)(32 + rowl) * nw + w] = s2l;
    partials[(long)(48 + rowl) * nw + w] = s2h;
  }
}

// ---------------- reduce partials -> stats[64] (sum[32], sumsq[32]) ----------------
__global__ __launch_bounds__(256) void k_reduce(const float* __restrict__ partials,
                                                int nw, float* __restrict__ stats) {
  __shared__ float sd[256];
  int c = blockIdx.x;
  const float* p = partials + (long)c * nw;
  float s = 0.f;
  for (int i = threadIdx.x; i < nw; i += 256) s += p[i];
  sd[threadIdx.x] = s; __syncthreads();
  for (int st = 128; st > 0; st >>= 1) {
    if (threadIdx.x < st) sd[threadIdx.x] += sd[threadIdx.x + st];
    __syncthreads();
  }
  if (threadIdx.x == 0) stats[c] = sd[0];
}

// ---------------- BN apply, in place on out ----------------
__global__ __launch_bounds__(256) void k_bn(float* __restrict__ out,
                                            const float* __restrict__ stats,
                                            const float* __restrict__ gamma,
                                            const float* __restrict__ beta, int nf) {
  __shared__ float sc[32], sh[32];
  if (threadIdx.x < 32) {
    int o = threadIdx.x;
    float inv_n = 1.0f / (float)nf;
    float mean = stats[o] * inv_n;
    float var = stats[32 + o] * inv_n - mean * mean;
    float rstd = rsqrtf(var + 1e-5f);
    float g = gamma[o] * rstd;
    sc[o] = g;
    sh[o] = beta[o] - mean * g;
  }
  __syncthreads();
  long total4 = (long)nf * 8;
  long idx0 = (long)blockIdx.x * 256 + threadIdx.x;
  int ob = ((int)idx0 & 7) * 4;           // constant per thread (stride % 8 == 0)
  fv4 scv = *(const fv4*)&sc[ob];
  fv4 shv = *(const fv4*)&sh[ob];
  for (long idx = idx0; idx < total4; idx += (long)gridDim.x * 256) {
    fv4 v = *((const fv4*)out + idx);
    v = v * scv + shv;
    *((fv4*)out + idx) = v;
  }
}

extern "C" void kernel_launch(void* const* d_in, const int* in_sizes, int n_in,
                              void* d_out, int out_size, void* d_ws, size_t ws_size,
                              hipStream_t stream) {
  const float* x     = (const float*)d_in[0];
  const float* bary  = (const float*)d_in[1];
  const int*   numt  = (const int*)d_in[2];
  const float* W     = (const float*)d_in[3];
  const float* bias  = (const float*)d_in[4];
  const float* gamma = (const float*)d_in[5];
  const float* beta  = (const float*)d_in[6];
  float* out = (float*)d_out;

  const int nf   = in_sizes[2];
  const int nt   = in_sizes[0] / 32;      // total samples
  const int nblk = (nf + SPAN - 1) / SPAN;
  const int nw   = nblk * 4;              // one partials column per wave
  const int nbS  = (nf + SCHUNK - 1) / SCHUNK;

  char* w = (char*)d_ws;
  int* offsets = (int*)w;
  size_t off1 = (4UL * (size_t)(nf + 1) + 255) & ~255UL;
  int* bsum = (int*)(w + off1);
  size_t off2 = (off1 + 4UL * (size_t)nbS + 255) & ~255UL;
  float* partials = (float*)(w + off2);
  size_t off3 = (off2 + 4UL * 64UL * (size_t)nw + 255) & ~255UL;
  float* stats = (float*)(w + off3);

  scan1<<<nbS, 256, 0, stream>>>(numt, nf, bsum);
  scan2<<<1, 256, 0, stream>>>(bsum, nbS);
  scan3<<<nbS, 256, 0, stream>>>(numt, nf, bsum, offsets);
  k_main<<<nblk, 256, 0, stream>>>(x, bary, W, bias, offsets, out, partials, nf, nt, nw);
  k_reduce<<<64, 256, 0, stream>>>(partials, nw, stats);
  k_bn<<<2048, 256, 0, stream>>>(out, stats, gamma, beta, nf);
}

// Round 11
// 97.044 us; speedup vs baseline: 1.4789x; 1.0079x over previous
//
#include <hip/hip_runtime.h>
#include <hip/hip_bf16.h>
#include <stdint.h>

typedef __attribute__((ext_vector_type(4))) float fv4;
typedef __attribute__((ext_vector_type(4))) short sv4;
typedef __attribute__((ext_vector_type(8))) short sv8;

#define SCHUNK 2048
#define NIT 4             // tiles per wave (even)
#define SPAN (64 * NIT)   // facets per block
#define PZB 108           // Z row pitch (shorts), validated

static __device__ __forceinline__ short f2bf(float f) {
  __hip_bfloat16 h = __float2bfloat16(f);   // HW v_cvt, RNE
  union { __hip_bfloat16 h; short s; } u; u.h = h;
  return u.s;
}

// ---------------- scan: offsets from num_texture (R1-validated) ----------------
__global__ __launch_bounds__(256) void scan1(const int* __restrict__ num, int nf,
                                             int* __restrict__ bsum) {
  __shared__ int sd[256];
  int b = blockIdx.x, tid = threadIdx.x;
  int base = b * SCHUNK + tid * 8;
  int s = 0;
#pragma unroll
  for (int j = 0; j < 8; ++j) { int i = base + j; if (i < nf) s += num[i]; }
  sd[tid] = s; __syncthreads();
  for (int st = 128; st > 0; st >>= 1) {
    if (tid < st) sd[tid] += sd[tid + st];
    __syncthreads();
  }
  if (tid == 0) bsum[b] = sd[0];
}

__global__ __launch_bounds__(256) void scan2(int* __restrict__ bsum, int nb) {
  __shared__ int sd[256];
  int tid = threadIdx.x;
  int v = (tid < nb) ? bsum[tid] : 0;
  sd[tid] = v; __syncthreads();
  for (int off = 1; off < 256; off <<= 1) {
    int t = (tid >= off) ? sd[tid - off] : 0;
    __syncthreads();
    sd[tid] += t;
    __syncthreads();
  }
  if (tid < nb) bsum[tid] = sd[tid] - v;   // exclusive prefix
}

__global__ __launch_bounds__(256) void scan3(const int* __restrict__ num, int nf,
                                             const int* __restrict__ bsum,
                                             int* __restrict__ offsets) {
  __shared__ int sc_[256];
  int b = blockIdx.x, tid = threadIdx.x;
  int base = b * SCHUNK + tid * 8;
  int loc[8]; int s = 0;
#pragma unroll
  for (int j = 0; j < 8; ++j) {
    loc[j] = (base + j < nf) ? num[base + j] : 0;
    s += loc[j];
  }
  sc_[tid] = s; __syncthreads();
  for (int off = 1; off < 256; off <<= 1) {
    int t = (tid >= off) ? sc_[tid - off] : 0;
    __syncthreads();
    sc_[tid] += t;
    __syncthreads();
  }
  int run = bsum[b] + sc_[tid] - s;
#pragma unroll
  for (int j = 0; j < 8; ++j) {
    if (base + j < nf) offsets[base + j] = run;
    run += loc[j];
  }
  if (b == gridDim.x - 1 && tid == 255) offsets[nf] = run;
}

// ---- pipelined register sets: expansion is byte-identical to R10's validated blocks ----
#define DECL_SET(S) \
  int st_##S, en_##S; \
  fv4 x0a_##S, x0b_##S, x1a_##S, x1b_##S, x2a_##S, x2b_##S; \
  float b00_##S, b01_##S, b02_##S, b10_##S, b11_##S, b12_##S, b20_##S, b21_##S, b22_##S;

#define LOAD_SET(S, T) do { \
  const int f_ = blk0 + (T) * 64 + wv * 16 + fl; \
  const int fa_ = f_ < nf ? f_ : nf; \
  const int fb_ = (f_ + 1) < nf ? (f_ + 1) : nf; \
  st_##S = offsets[fa_]; \
  en_##S = offsets[fb_]; \
  const int s3_ = 3 * f_; \
  const int sbase_ = (f_ < nf && s3_ + 3 <= nt) ? s3_ : 0; \
  const float* xp0_ = x + (size_t)(sbase_ + 0) * 32 + cb; \
  const float* xp1_ = x + (size_t)(sbase_ + 1) * 32 + cb; \
  const float* xp2_ = x + (size_t)(sbase_ + 2) * 32 + cb; \
  x0a_##S = *(const fv4*)(xp0_); x0b_##S = *(const fv4*)(xp0_ + 4); \
  x1a_##S = *(const fv4*)(xp1_); x1b_##S = *(const fv4*)(xp1_ + 4); \
  x2a_##S = *(const fv4*)(xp2_); x2b_##S = *(const fv4*)(xp2_ + 4); \
  const float* bp0_ = bary + (size_t)(sbase_ + 0) * 3; \
  const float* bp1_ = bary + (size_t)(sbase_ + 1) * 3; \
  const float* bp2_ = bary + (size_t)(sbase_ + 2) * 3; \
  b00_##S = bp0_[0]; b01_##S = bp0_[1]; b02_##S = bp0_[2]; \
  b10_##S = bp1_[0]; b11_##S = bp1_[1]; b12_##S = bp1_[2]; \
  b20_##S = bp2_[0]; b21_##S = bp2_[1]; b22_##S = bp2_[2]; \
} while (0)

#define COMPUTE_SET(S, T) do { \
  const int f0t = blk0 + (T) * 64 + wv * 16; \
  const int f_ = f0t + fl; \
  const int nm_my = en_##S - st_##S; \
  float z0[8], z1[8], z2[8]; \
  _Pragma("unroll") \
  for (int j = 0; j < 8; ++j) { z0[j] = 0.f; z1[j] = 0.f; z2[j] = 0.f; } \
  if (nm_my == 3 && st_##S == 3 * f_) { \
    _Pragma("unroll") \
    for (int j = 0; j < 4; ++j) { \
      z0[j]     += x0a_##S[j] * b00_##S; z1[j]     += x0a_##S[j] * b01_##S; z2[j]     += x0a_##S[j] * b02_##S; \
      z0[4 + j] += x0b_##S[j] * b00_##S; z1[4 + j] += x0b_##S[j] * b01_##S; z2[4 + j] += x0b_##S[j] * b02_##S; \
    } \
    _Pragma("unroll") \
    for (int j = 0; j < 4; ++j) { \
      z0[j]     += x1a_##S[j] * b10_##S; z1[j]     += x1a_##S[j] * b11_##S; z2[j]     += x1a_##S[j] * b12_##S; \
      z0[4 + j] += x1b_##S[j] * b10_##S; z1[4 + j] += x1b_##S[j] * b11_##S; z2[4 + j] += x1b_##S[j] * b12_##S; \
    } \
    _Pragma("unroll") \
    for (int j = 0; j < 4; ++j) { \
      z0[j]     += x2a_##S[j] * b20_##S; z1[j]     += x2a_##S[j] * b21_##S; z2[j]     += x2a_##S[j] * b22_##S; \
      z0[4 + j] += x2b_##S[j] * b20_##S; z1[4 + j] += x2b_##S[j] * b21_##S; z2[4 + j] += x2b_##S[j] * b22_##S; \
    } \
  } else { \
    for (int t2 = st_##S; t2 < en_##S; ++t2) { \
      const float* xp_ = x + (size_t)t2 * 32 + cb; \
      fv4 xa_ = *(const fv4*)(xp_); \
      fv4 xb_ = *(const fv4*)(xp_ + 4); \
      const float* bp_ = bary + (size_t)t2 * 3; \
      float b0_ = bp_[0], b1_ = bp_[1], b2_ = bp_[2]; \
      _Pragma("unroll") \
      for (int j = 0; j < 4; ++j) { \
        z0[j]     += xa_[j] * b0_; z1[j]     += xa_[j] * b1_; z2[j]     += xa_[j] * b2_; \
        z0[4 + j] += xb_[j] * b0_; z1[4 + j] += xb_[j] * b1_; z2[4 + j] += xb_[j] * b2_; \
      } \
    } \
  } \
  short* zr_ = &Zw[fl * PZB + cb]; \
  _Pragma("unroll") \
  for (int g = 0; g < 2; ++g) { \
    sv4 p0_, p1_, p2_; \
    _Pragma("unroll") \
    for (int j = 0; j < 4; ++j) { \
      p0_[j] = f2bf(z0[g * 4 + j]); \
      p1_[j] = f2bf(z1[g * 4 + j]); \
      p2_[j] = f2bf(z2[g * 4 + j]); \
    } \
    *(sv4*)(zr_ + g * 4)      = p0_; \
    *(sv4*)(zr_ + 32 + g * 4) = p1_; \
    *(sv4*)(zr_ + 64 + g * 4) = p2_; \
  } \
  __builtin_amdgcn_wave_barrier(); \
  fv4 acc0 = (fv4){0.f, 0.f, 0.f, 0.f}; \
  fv4 acc1 = (fv4){0.f, 0.f, 0.f, 0.f}; \
  _Pragma("unroll") \
  for (int kb = 0; kb < 3; ++kb) { \
    const int cko = kb * 32 + grp * 4; \
    sv8 bfr0, bfr1, afr; \
    { \
      const short* wr_ = &W2[rowl * PZB + cko]; \
      sv4 lo_ = *(const sv4*)(wr_), hi_ = *(const sv4*)(wr_ + 16); \
      _Pragma("unroll") \
      for (int j = 0; j < 4; ++j) { bfr0[j] = lo_[j]; bfr0[4 + j] = hi_[j]; } \
    } \
    { \
      const short* wr_ = &W2[(16 + rowl) * PZB + cko]; \
      sv4 lo_ = *(const sv4*)(wr_), hi_ = *(const sv4*)(wr_ + 16); \
      _Pragma("unroll") \
      for (int j = 0; j < 4; ++j) { bfr1[j] = lo_[j]; bfr1[4 + j] = hi_[j]; } \
    } \
    { \
      const short* zr2_ = &Zw[rowl * PZB + cko]; \
      sv4 lo_ = *(const sv4*)(zr2_), hi_ = *(const sv4*)(zr2_ + 16); \
      _Pragma("unroll") \
      for (int j = 0; j < 4; ++j) { afr[j] = lo_[j]; afr[4 + j] = hi_[j]; } \
    } \
    acc0 = __builtin_amdgcn_mfma_f32_16x16x32_bf16(afr, bfr0, acc0, 0, 0, 0); \
    acc1 = __builtin_amdgcn_mfma_f32_16x16x32_bf16(afr, bfr1, acc1, 0, 0, 0); \
  } \
  _Pragma("unroll") \
  for (int r = 0; r < 4; ++r) { \
    int row_ = grp * 4 + r; \
    int fr_ = f0t + row_; \
    int nm_ = __shfl(nm_my, row_ * 4, 64); \
    float inv_ = 1.0f / (float)(nm_ > 1 ? nm_ : 1); \
    if (fr_ < nf) { \
      float v0_ = fmaxf(acc0[r] * inv_ + bo0, 0.f); \
      float v1_ = fmaxf(acc1[r] * inv_ + bo1, 0.f); \
      out[fr_ * 32 + rowl]      = v0_; \
      out[fr_ * 32 + 16 + rowl] = v1_; \
      s1l += v0_; s2l += v0_ * v0_; \
      s1h += v1_; s2h += v1_ * v1_; \
    } \
  } \
  __builtin_amdgcn_wave_barrier(); \
} while (0)

// ---------------- main: wave-autonomous multi-tile; 2-deep pipelined loads ----------------
__global__ __launch_bounds__(256) void k_main(
    const float* __restrict__ x, const float* __restrict__ bary,
    const float* __restrict__ W, const float* __restrict__ bias,
    const int* __restrict__ offsets, float* __restrict__ out,
    float* __restrict__ partials, int nf, int nt, int nw)
{
  __shared__ short W2[32 * PZB];       // 6912 B, read-only after prologue
  __shared__ short Z[4 * 16 * PZB];    // 13824 B; 4 disjoint wave-private quarters

  const int tid = threadIdx.x;
  const int lane = tid & 63;
  const int wv = tid >> 6;
  short* Zw = &Z[wv * 16 * PZB];

  // ---- prologue: stage W2[o*PZB + k*32 + c] = bf16(W[o*96 + c*3 + k]) (validated) ----
  for (int idx = tid; idx < 3072; idx += 256) {
    int o = idx / 96;
    int ck = idx - o * 96;
    int k = ck >> 5, c = ck & 31;
    W2[o * PZB + ck] = f2bf(W[o * 96 + c * 3 + k]);
  }
  __syncthreads();   // the ONLY block barrier

  const int fl = lane >> 2;            // 0..15  (fold row)
  const int cb = (lane & 3) * 8;       // 0,8,16,24 (fold channel base)
  const int rowl = lane & 15;          // GEMM/epilogue col
  const int grp = lane >> 4;           // GEMM/epilogue row group
  const int blk0 = blockIdx.x * SPAN;

  float bo0 = bias[rowl];
  float bo1 = bias[16 + rowl];
  float s1l = 0.f, s1h = 0.f, s2l = 0.f, s2h = 0.f;

  DECL_SET(A)
  DECL_SET(B)

  LOAD_SET(A, 0);
#pragma unroll
  for (int tt = 0; tt < NIT / 2; ++tt) {
    const int t0 = 2 * tt, t1 = 2 * tt + 1;
    LOAD_SET(B, t1);                  // issue next tile's loads before computing current
    COMPUTE_SET(A, t0);
    if (t1 + 1 < NIT) LOAD_SET(A, t1 + 1);
    COMPUTE_SET(B, t1);
  }

  // ---- per-wave stats -> one partials column (R8-validated reduce) ----
  s1l += __shfl_xor(s1l, 16, 64); s1l += __shfl_xor(s1l, 32, 64);
  s1h += __shfl_xor(s1h, 16, 64); s1h += __shfl_xor(s1h, 32, 64);
  s2l += __shfl_xor(s2l, 16, 64); s2l += __shfl_xor(s2l, 32, 64);
  s2h += __shfl_xor(s2h, 16, 64); s2h += __shfl_xor(s2h, 32, 64);
  if (grp == 0) {
    int w = blockIdx.x * 4 + wv;
    partials[(long)(rowl)      * nw + w] = s1l;
    partials[(long)(16 + rowl) * nw + w] = s1h;
    partials[(long)(32 + rowl) * nw + w] = s2l;
    partials[(long)(48 + rowl) * nw + w] = s2h;
  }
}

// ---------------- reduce partials -> stats[64] (sum[32], sumsq[32]) ----------------
__global__ __launch_bounds__(256) void k_reduce(const float* __restrict__ partials,
                                                int nw, float* __restrict__ stats) {
  __shared__ float sd[256];
  int c = blockIdx.x;
  const float* p = partials + (long)c * nw;
  float s = 0.f;
  for (int i = threadIdx.x; i < nw; i += 256) s += p[i];
  sd[threadIdx.x] = s; __syncthreads();
  for (int st = 128; st > 0; st >>= 1) {
    if (threadIdx.x < st) sd[threadIdx.x] += sd[threadIdx.x + st];
    __syncthreads();
  }
  if (threadIdx.x == 0) stats[c] = sd[0];
}

// ---------------- BN apply, in place on out ----------------
__global__ __launch_bounds__(256) void k_bn(float* __restrict__ out,
                                            const float* __restrict__ stats,
                                            const float* __restrict__ gamma,
                                            const float* __restrict__ beta, int nf) {
  __shared__ float sc[32], sh[32];
  if (threadIdx.x < 32) {
    int o = threadIdx.x;
    float inv_n = 1.0f / (float)nf;
    float mean = stats[o] * inv_n;
    float var = stats[32 + o] * inv_n - mean * mean;
    float rstd = rsqrtf(var + 1e-5f);
    float g = gamma[o] * rstd;
    sc[o] = g;
    sh[o] = beta[o] - mean * g;
  }
  __syncthreads();
  long total4 = (long)nf * 8;
  long idx0 = (long)blockIdx.x * 256 + threadIdx.x;
  int ob = ((int)idx0 & 7) * 4;           // constant per thread (stride % 8 == 0)
  fv4 scv = *(const fv4*)&sc[ob];
  fv4 shv = *(const fv4*)&sh[ob];
  for (long idx = idx0; idx < total4; idx += (long)gridDim.x * 256) {
    fv4 v = *((const fv4*)out + idx);
    v = v * scv + shv;
    *((fv4*)out + idx) = v;
  }
}

extern "C" void kernel_launch(void* const* d_in, const int* in_sizes, int n_in,
                              void* d_out, int out_size, void* d_ws, size_t ws_size,
                              hipStream_t stream) {
  const float* x     = (const float*)d_in[0];
  const float* bary  = (const float*)d_in[1];
  const int*   numt  = (const int*)d_in[2];
  const float* W     = (const float*)d_in[3];
  const float* bias  = (const float*)d_in[4];
  const float* gamma = (const float*)d_in[5];
  const float* beta  = (const float*)d_in[6];
  float* out = (float*)d_out;

  const int nf   = in_sizes[2];
  const int nt   = in_sizes[0] / 32;      // total samples
  const int nblk = (nf + SPAN - 1) / SPAN;
  const int nw   = nblk * 4;              // one partials column per wave
  const int nbS  = (nf + SCHUNK - 1) / SCHUNK;

  char* w = (char*)d_ws;
  int* offsets = (int*)w;
  size_t off1 = (4UL * (size_t)(nf + 1) + 255) & ~255UL;
  int* bsum = (int*)(w + off1);
  size_t off2 = (off1 + 4UL * (size_t)nbS + 255) & ~255UL;
  float* partials = (float*)(w + off2);
  size_t off3 = (off2 + 4UL * 64UL * (size_t)nw + 255) & ~255UL;
  float* stats = (float*)(w + off3);

  scan1<<<nbS, 256, 0, stream>>>(numt, nf, bsum);
  scan2<<<1, 256, 0, stream>>>(bsum, nbS);
  scan3<<<nbS, 256, 0, stream>>>(numt, nf, bsum, offsets);
  k_main<<<nblk, 256, 0, stream>>>(x, bary, W, bias, offsets, out, partials, nf, nt, nw);
  k_reduce<<<64, 256, 0, stream>>>(partials, nw, stats);
  k_bn<<<2048, 256, 0, stream>>>(out, stats, gamma, beta, nf);
}